// Round 1
// baseline (332.261 us; speedup 1.0000x reference)
//
#include <hip/hip_runtime.h>
#include <math.h>

// GraphAttentionLayer, N=8192, D=256, fp32.
// Exact algorithmic reformulation:
//   h = x@W + b ; s1 = h@a1 ; s2 = h@a2 ; c_i = s1_i + a_b
//   w_ij = exp(leaky(c_i + s2_j)) = [s2_j >= -c_i] exp(c_i)E_j + [s2_j < -c_i] exp(.01c_i)F_j
//   with E_j = exp(s2_j), F_j = exp(.01 s2_j).
// Counting-sort j by s2_j into 8192 value-buckets; per-bucket suffix sums of E_j h_j
// (SE) and prefix sums of F_j h_j (SF) + scalar analogs give each output row with
// two vector lookups plus an exactly-evaluated boundary bucket. O(N*D) total.

#define NN 8192
#define DD 256
#define NB 8192
#define RANGE 8.0f
#define SCALE (NB / (2.0f * RANGE)) /* 512 buckets per unit*16 */
#define NEG_SLOPE 0.01f

__device__ __forceinline__ int bucket_of(float v) {
    v = fminf(fmaxf(v, -RANGE), RANGE);
    int b = (int)floorf((v + RANGE) * SCALE);
    if (b < 0) b = 0;
    if (b > NB - 1) b = NB - 1;
    return b;
}

// ---------------------------------------------------------------- KA: h = x@W+b, s1, s2, E, F, hist
__global__ __launch_bounds__(256) void ka_gemm(
    const float* __restrict__ x, const float* __restrict__ W,
    const float* __restrict__ bfc, const float* __restrict__ a1,
    const float* __restrict__ a2,
    float* __restrict__ h, float* __restrict__ s1, float* __restrict__ s2,
    float* __restrict__ E, float* __restrict__ F, int* __restrict__ cnt)
{
    const int d = threadIdx.x;
    const int row0 = blockIdx.x * 16;
    float acc[16];
#pragma unroll
    for (int r = 0; r < 16; ++r) acc[r] = 0.f;

    for (int k4 = 0; k4 < DD / 4; ++k4) {
        const float w0 = W[(4 * k4 + 0) * DD + d];
        const float w1 = W[(4 * k4 + 1) * DD + d];
        const float w2 = W[(4 * k4 + 2) * DD + d];
        const float w3 = W[(4 * k4 + 3) * DD + d];
#pragma unroll
        for (int r = 0; r < 16; ++r) {
            const float4 xv = *reinterpret_cast<const float4*>(&x[(size_t)(row0 + r) * DD + 4 * k4]);
            acc[r] = fmaf(xv.x, w0, fmaf(xv.y, w1, fmaf(xv.z, w2, fmaf(xv.w, w3, acc[r]))));
        }
    }

    const float bb = bfc[d];
    const float a1d = a1[d], a2d = a2[d];
    __shared__ float part1[4][16];
    __shared__ float part2[4][16];
    const int wave = d >> 6, lane = d & 63;

#pragma unroll
    for (int r = 0; r < 16; ++r) {
        acc[r] += bb;
        h[(size_t)(row0 + r) * DD + d] = acc[r];
        float v1 = acc[r] * a1d;
        float v2 = acc[r] * a2d;
#pragma unroll
        for (int off = 32; off; off >>= 1) {
            v1 += __shfl_xor(v1, off, 64);
            v2 += __shfl_xor(v2, off, 64);
        }
        if (lane == 0) { part1[wave][r] = v1; part2[wave][r] = v2; }
    }
    __syncthreads();
    if (d < 32) {
        const int r = d & 15, which = d >> 4;
        if (which == 0) {
            s1[row0 + r] = part1[0][r] + part1[1][r] + part1[2][r] + part1[3][r];
        } else {
            const float s = part2[0][r] + part2[1][r] + part2[2][r] + part2[3][r];
            s2[row0 + r] = s;
            E[row0 + r] = expf(s);
            F[row0 + r] = expf(NEG_SLOPE * s);
            atomicAdd(&cnt[bucket_of(s)], 1);
        }
    }
}

// ---------------------------------------------------------------- KB: exclusive scan of cnt -> boff (+cursor copy)
__global__ __launch_bounds__(256) void kb_scan(int* __restrict__ cnt, int* __restrict__ boff)
{
    __shared__ int lds[256];
    const int t = threadIdx.x;
    const int base = t * 32;
    int loc[32];
    int s = 0;
#pragma unroll
    for (int k = 0; k < 32; ++k) { loc[k] = s; s += cnt[base + k]; }
    lds[t] = s;
    __syncthreads();
    for (int off = 1; off < 256; off <<= 1) {
        const int v = (t >= off) ? lds[t - off] : 0;
        __syncthreads();
        lds[t] += v;
        __syncthreads();
    }
    const int excl = (t > 0) ? lds[t - 1] : 0;
#pragma unroll
    for (int k = 0; k < 32; ++k) {
        const int val = excl + loc[k];
        boff[base + k] = val;
        cnt[base + k] = val; // becomes the scatter cursor
    }
    if (t == 0) boff[NB] = NN;
}

// ---------------------------------------------------------------- KC: counting-sort scatter
__global__ __launch_bounds__(256) void kc_scatter(
    const float* __restrict__ s2, int* __restrict__ cursor, int* __restrict__ perm)
{
    const int j = blockIdx.x * blockDim.x + threadIdx.x;
    if (j < NN) {
        const int b = bucket_of(s2[j]);
        const int p = atomicAdd(&cursor[b], 1);
        perm[p] = j;
    }
}

// ---------------------------------------------------------------- KD1: per-chunk totals (32 buckets/chunk)
__global__ __launch_bounds__(320) void kd1_tot(
    const float* __restrict__ h, const float* __restrict__ E, const float* __restrict__ F,
    const int* __restrict__ perm, const int* __restrict__ boff,
    float* __restrict__ TE, float* __restrict__ TF,
    float* __restrict__ sTE, float* __restrict__ sTF)
{
    const int c = blockIdx.x;
    const int p0 = boff[c * 32], p1 = boff[(c + 1) * 32];
    const int t = threadIdx.x;
    if (t < 256) {
        float te = 0.f, tf = 0.f;
        for (int p = p0; p < p1; ++p) {
            const int j = perm[p];
            const float hv = h[(size_t)j * DD + t];
            te = fmaf(E[j], hv, te);
            tf = fmaf(F[j], hv, tf);
        }
        TE[c * DD + t] = te;
        TF[c * DD + t] = tf;
    } else if (t == 256) {
        float se = 0.f, sf = 0.f;
        for (int p = p0; p < p1; ++p) { const int j = perm[p]; se += E[j]; sf += F[j]; }
        sTE[c] = se;
        sTF[c] = sf;
    }
}

// ---------------------------------------------------------------- KD2: chunk-level scans (in-place -> exclusive offsets)
__global__ __launch_bounds__(256) void kd2_scan(
    float* __restrict__ TE, float* __restrict__ TF,
    float* __restrict__ sTE, float* __restrict__ sTF,
    float* __restrict__ SE, float* __restrict__ sden_suf)
{
    const int t = threadIdx.x;
    float runE = 0.f;
    for (int c = 255; c >= 0; --c) { const float v = TE[c * DD + t]; TE[c * DD + t] = runE; runE += v; }
    float runF = 0.f;
    for (int c = 0; c < 256; ++c) { const float v = TF[c * DD + t]; TF[c * DD + t] = runF; runF += v; }
    SE[(size_t)NB * DD + t] = 0.f; // SE[NB] row = 0

    __shared__ float a[256];
    __shared__ float b[256];
    a[t] = sTE[t];
    b[t] = sTF[t];
    __syncthreads();
    for (int off = 1; off < 256; off <<= 1) {
        const float va = (t + off < 256) ? a[t + off] : 0.f; // suffix scan
        const float vb = (t >= off) ? b[t - off] : 0.f;      // prefix scan
        __syncthreads();
        a[t] += va;
        b[t] += vb;
        __syncthreads();
    }
    sTE[t] = (t + 1 < 256) ? a[t + 1] : 0.f; // exclusive suffix offset
    sTF[t] = (t > 0) ? b[t - 1] : 0.f;       // exclusive prefix offset
    if (t == 0) sden_suf[NB] = 0.f;
}

// ---------------------------------------------------------------- KD3: per-bucket SE (suffix) / SF (prefix) arrays
__global__ __launch_bounds__(320) void kd3_write(
    const float* __restrict__ h, const float* __restrict__ E, const float* __restrict__ F,
    const int* __restrict__ perm, const int* __restrict__ boff,
    const float* __restrict__ TE, const float* __restrict__ TF,
    const float* __restrict__ sTE, const float* __restrict__ sTF,
    float* __restrict__ SE, float* __restrict__ SF,
    float* __restrict__ sden_suf, float* __restrict__ sden_pre)
{
    const int c = blockIdx.x;
    const int blo = c * 32, bhi = blo + 32;
    const int t = threadIdx.x;
    if (t < 256) {
        float runE = TE[c * DD + t];
        for (int b = bhi - 1; b >= blo; --b) {
            for (int p = boff[b + 1] - 1; p >= boff[b]; --p) {
                const int j = perm[p];
                runE = fmaf(E[j], h[(size_t)j * DD + t], runE);
            }
            SE[(size_t)b * DD + t] = runE;
        }
        float runF = TF[c * DD + t];
        for (int b = blo; b < bhi; ++b) {
            SF[(size_t)b * DD + t] = runF;
            for (int p = boff[b]; p < boff[b + 1]; ++p) {
                const int j = perm[p];
                runF = fmaf(F[j], h[(size_t)j * DD + t], runF);
            }
        }
    } else if (t == 256) {
        float rE = sTE[c];
        for (int b = bhi - 1; b >= blo; --b) {
            for (int p = boff[b + 1] - 1; p >= boff[b]; --p) rE += E[perm[p]];
            sden_suf[b] = rE;
        }
        float rF = sTF[c];
        for (int b = blo; b < bhi; ++b) {
            sden_pre[b] = rF;
            for (int p = boff[b]; p < boff[b + 1]; ++p) rF += F[perm[p]];
        }
    }
}

// ---------------------------------------------------------------- KE: output rows
__global__ __launch_bounds__(256) void ke_out(
    const float* __restrict__ h, const float* __restrict__ s1, const float* __restrict__ s2,
    const float* __restrict__ E, const float* __restrict__ F,
    const int* __restrict__ perm, const int* __restrict__ boff,
    const float* __restrict__ SE, const float* __restrict__ SF,
    const float* __restrict__ sden_suf, const float* __restrict__ sden_pre,
    const float* __restrict__ ab, float* __restrict__ out)
{
    const int i = blockIdx.x;
    const int t = threadIdx.x;
    const float c = s1[i] + ab[0];
    const float tau = -c;
    const int Bt = bucket_of(tau);
    const float A = expf(c);
    const float Alo = expf(NEG_SLOPE * c);

    float num = A * SE[(size_t)(Bt + 1) * DD + t] + Alo * SF[(size_t)Bt * DD + t];
    float den = A * sden_suf[Bt + 1] + Alo * sden_pre[Bt];

    const int p0 = boff[Bt], p1 = boff[Bt + 1];
    for (int p = p0; p < p1; ++p) {
        const int j = perm[p];
        const float hv = h[(size_t)j * DD + t];
        if (s2[j] >= tau) {
            const float w = A * E[j];
            num = fmaf(w, hv, num);
            den += w;
        } else {
            const float w = Alo * F[j];
            num = fmaf(w, hv, num);
            den += w;
        }
    }
    out[(size_t)i * DD + t] = num / den;
}

// ----------------------------------------------------------------
extern "C" void kernel_launch(void* const* d_in, const int* in_sizes, int n_in,
                              void* d_out, int out_size, void* d_ws, size_t ws_size,
                              hipStream_t stream)
{
    const float* x   = (const float*)d_in[0];
    const float* W   = (const float*)d_in[1];
    const float* bfc = (const float*)d_in[2];
    const float* a1  = (const float*)d_in[3];
    const float* a2  = (const float*)d_in[4];
    const float* ab  = (const float*)d_in[5];
    float* out = (float*)d_out;

    float* h        = (float*)d_ws;                 // [N][D]
    float* SE       = h + (size_t)NN * DD;          // [NB+1][D]
    float* SF       = SE + (size_t)(NB + 1) * DD;   // [NB+1][D]
    float* TE       = SF + (size_t)(NB + 1) * DD;   // [256][D]
    float* TF       = TE + 256 * DD;                // [256][D]
    float* s1       = TF + 256 * DD;                // [N]
    float* s2       = s1 + NN;                      // [N]
    float* E        = s2 + NN;                      // [N]
    float* F        = E + NN;                       // [N]
    float* sden_suf = F + NN;                       // [NB+1]
    float* sden_pre = sden_suf + (NB + 1);          // [NB+1]
    float* sTE      = sden_pre + (NB + 1);          // [256]
    float* sTF      = sTE + 256;                    // [256]
    int* cnt        = (int*)(sTF + 256);            // [NB]
    int* boff       = cnt + NB;                     // [NB+1]
    int* perm       = boff + (NB + 1);              // [N]

    hipMemsetAsync(cnt, 0, NB * sizeof(int), stream);
    ka_gemm<<<NN / 16, 256, 0, stream>>>(x, W, bfc, a1, a2, h, s1, s2, E, F, cnt);
    kb_scan<<<1, 256, 0, stream>>>(cnt, boff);
    kc_scatter<<<NN / 256, 256, 0, stream>>>(s2, cnt, perm);
    kd1_tot<<<256, 320, 0, stream>>>(h, E, F, perm, boff, TE, TF, sTE, sTF);
    kd2_scan<<<1, 256, 0, stream>>>(TE, TF, sTE, sTF, SE, sden_suf);
    kd3_write<<<256, 320, 0, stream>>>(h, E, F, perm, boff, TE, TF, sTE, sTF, SE, SF, sden_suf, sden_pre);
    ke_out<<<NN, 256, 0, stream>>>(h, s1, s2, E, F, perm, boff, SE, SF, sden_suf, sden_pre, ab, out);
}

// Round 2
// 173.783 us; speedup vs baseline: 1.9119x; 1.9119x over previous
//
#include <hip/hip_runtime.h>
#include <math.h>

// GraphAttentionLayer, N=8192, D=256, fp32. Exact reformulation:
//   h = x@W + b ; s1 = h@a1 ; s2 = h@a2 ; c_i = s1_i + a_b
//   w_ij = [s2_j >= -c_i] exp(c_i)E_j + [s2_j < -c_i] exp(.01c_i)F_j,
//   E_j = exp(s2_j), F_j = exp(.01 s2_j).
// Counting-sort j by s2_j (8192 value buckets); then POSITION-indexed
// suffix/prefix scans PSE/PSF over the sorted order (uniform 16-element
// chunks, fully pipelined gathers) replace the bucket-indexed SE/SF of R0,
// whose serial per-bucket dependent chains were 133us at 2% HBM.

#define NN 8192
#define DD 256
#define NB 8192
#define CH 512           /* scan chunks */
#define POS (NN / CH)    /* 16 positions per chunk */
#define RANGE 8.0f
#define SCALE (NB / (2.0f * RANGE))
#define NEG_SLOPE 0.01f

__device__ __forceinline__ int bucket_of(float v) {
    v = fminf(fmaxf(v, -RANGE), RANGE);
    int b = (int)floorf((v + RANGE) * SCALE);
    if (b < 0) b = 0;
    if (b > NB - 1) b = NB - 1;
    return b;
}

// ---------------------------------------------------------------- KA: h = x@W+b, s1, s2, E, F, hist
__global__ __launch_bounds__(256) void ka_gemm(
    const float* __restrict__ x, const float* __restrict__ W,
    const float* __restrict__ bfc, const float* __restrict__ a1,
    const float* __restrict__ a2,
    float* __restrict__ h, float* __restrict__ s1, float* __restrict__ s2,
    float* __restrict__ E, float* __restrict__ F, int* __restrict__ cnt)
{
    const int d = threadIdx.x;
    const int row0 = blockIdx.x * 16;
    float acc[16];
#pragma unroll
    for (int r = 0; r < 16; ++r) acc[r] = 0.f;

    for (int k4 = 0; k4 < DD / 4; ++k4) {
        const float w0 = W[(4 * k4 + 0) * DD + d];
        const float w1 = W[(4 * k4 + 1) * DD + d];
        const float w2 = W[(4 * k4 + 2) * DD + d];
        const float w3 = W[(4 * k4 + 3) * DD + d];
#pragma unroll
        for (int r = 0; r < 16; ++r) {
            const float4 xv = *reinterpret_cast<const float4*>(&x[(size_t)(row0 + r) * DD + 4 * k4]);
            acc[r] = fmaf(xv.x, w0, fmaf(xv.y, w1, fmaf(xv.z, w2, fmaf(xv.w, w3, acc[r]))));
        }
    }

    const float bb = bfc[d];
    const float a1d = a1[d], a2d = a2[d];
    __shared__ float part1[4][16];
    __shared__ float part2[4][16];
    const int wave = d >> 6, lane = d & 63;

#pragma unroll
    for (int r = 0; r < 16; ++r) {
        acc[r] += bb;
        h[(size_t)(row0 + r) * DD + d] = acc[r];
        float v1 = acc[r] * a1d;
        float v2 = acc[r] * a2d;
#pragma unroll
        for (int off = 32; off; off >>= 1) {
            v1 += __shfl_xor(v1, off, 64);
            v2 += __shfl_xor(v2, off, 64);
        }
        if (lane == 0) { part1[wave][r] = v1; part2[wave][r] = v2; }
    }
    __syncthreads();
    if (d < 32) {
        const int r = d & 15, which = d >> 4;
        if (which == 0) {
            s1[row0 + r] = part1[0][r] + part1[1][r] + part1[2][r] + part1[3][r];
        } else {
            const float s = part2[0][r] + part2[1][r] + part2[2][r] + part2[3][r];
            s2[row0 + r] = s;
            E[row0 + r] = expf(s);
            F[row0 + r] = expf(NEG_SLOPE * s);
            atomicAdd(&cnt[bucket_of(s)], 1);
        }
    }
}

// ---------------------------------------------------------------- KB: exclusive scan cnt -> boff (+cursor)
__global__ __launch_bounds__(256) void kb_scan(int* __restrict__ cnt, int* __restrict__ boff)
{
    __shared__ int lds[256];
    const int t = threadIdx.x;
    const int base = t * 32;
    int loc[32];
    int s = 0;
#pragma unroll
    for (int k = 0; k < 32; ++k) { loc[k] = s; s += cnt[base + k]; }
    lds[t] = s;
    __syncthreads();
    for (int off = 1; off < 256; off <<= 1) {
        const int v = (t >= off) ? lds[t - off] : 0;
        __syncthreads();
        lds[t] += v;
        __syncthreads();
    }
    const int excl = (t > 0) ? lds[t - 1] : 0;
#pragma unroll
    for (int k = 0; k < 32; ++k) {
        const int val = excl + loc[k];
        boff[base + k] = val;
        cnt[base + k] = val; // scatter cursor
    }
    if (t == 0) boff[NB] = NN;
}

// ---------------------------------------------------------------- KC: counting-sort scatter
__global__ __launch_bounds__(256) void kc_scatter(
    const float* __restrict__ s2, int* __restrict__ cursor, int* __restrict__ perm)
{
    const int j = blockIdx.x * blockDim.x + threadIdx.x;
    if (j < NN) {
        const int b = bucket_of(s2[j]);
        const int p = atomicAdd(&cursor[b], 1);
        perm[p] = j;
    }
}

// ---------------------------------------------------------------- KD1: per-chunk totals over sorted positions
__global__ __launch_bounds__(256) void kd1_tot(
    const float* __restrict__ h, const float* __restrict__ E, const float* __restrict__ F,
    const int* __restrict__ perm,
    float* __restrict__ TE, float* __restrict__ TF,
    float* __restrict__ sTE, float* __restrict__ sTF)
{
    const int c = blockIdx.x;
    const int t = threadIdx.x;
    __shared__ int jj[POS];
    __shared__ float Ee[POS], Ff[POS];
    if (t < POS) {
        const int j = perm[c * POS + t];
        jj[t] = j; Ee[t] = E[j]; Ff[t] = F[j];
    }
    __syncthreads();
    float te = 0.f, tf = 0.f;
#pragma unroll
    for (int k = 0; k < POS; ++k) {
        const float hv = h[(size_t)jj[k] * DD + t];
        te = fmaf(Ee[k], hv, te);
        tf = fmaf(Ff[k], hv, tf);
    }
    TE[c * DD + t] = te;
    TF[c * DD + t] = tf;
    if (t == 0) {
        float se = 0.f, sf = 0.f;
#pragma unroll
        for (int k = 0; k < POS; ++k) { se += Ee[k]; sf += Ff[k]; }
        sTE[c] = se; sTF[c] = sf;
    }
}

// ---------------------------------------------------------------- KD2: chunk scans -> exclusive bases
__global__ __launch_bounds__(512) void kd2_scan(
    float* __restrict__ TE, float* __restrict__ TF,
    float* __restrict__ sTE, float* __restrict__ sTF,
    float* __restrict__ PSE, float* __restrict__ PSF,
    float* __restrict__ psE, float* __restrict__ psF)
{
    const int t = threadIdx.x;
    if (t < 256) {
        float run = 0.f;
        for (int c = CH - 1; c >= 0; --c) { const float v = TE[c * DD + t]; TE[c * DD + t] = run; run += v; }
        PSE[(size_t)NN * DD + t] = 0.f;   // suffix beyond the end = 0
    } else {
        const int d = t - 256;
        float run = 0.f;
        for (int c = 0; c < CH; ++c) { const float v = TF[c * DD + d]; TF[c * DD + d] = run; run += v; }
        PSF[(size_t)NN * DD + d] = run;   // full prefix total
    }
    __shared__ float a[CH];
    __shared__ float b[CH];
    a[t] = sTE[t];
    b[t] = sTF[t];
    __syncthreads();
    for (int off = 1; off < CH; off <<= 1) {
        const float va = (t + off < CH) ? a[t + off] : 0.f; // suffix scan
        const float vb = (t >= off) ? b[t - off] : 0.f;     // prefix scan
        __syncthreads();
        a[t] += va;
        b[t] += vb;
        __syncthreads();
    }
    sTE[t] = (t + 1 < CH) ? a[t + 1] : 0.f; // exclusive suffix base
    sTF[t] = (t > 0) ? b[t - 1] : 0.f;      // exclusive prefix base
    if (t == 0) psE[NN] = 0.f;
    if (t == CH - 1) psF[NN] = b[CH - 1];
}

// ---------------------------------------------------------------- KD3: position-indexed PSE/PSF (+ scalar psE/psF)
__global__ __launch_bounds__(256) void kd3_write(
    const float* __restrict__ h, const float* __restrict__ E, const float* __restrict__ F,
    const int* __restrict__ perm,
    const float* __restrict__ TE, const float* __restrict__ TF,
    const float* __restrict__ sTE, const float* __restrict__ sTF,
    float* __restrict__ PSE, float* __restrict__ PSF,
    float* __restrict__ psE, float* __restrict__ psF)
{
    const int c = blockIdx.x;
    const int t = threadIdx.x;
    __shared__ int jj[POS];
    __shared__ float Ee[POS], Ff[POS];
    if (t < POS) {
        const int j = perm[c * POS + t];
        jj[t] = j; Ee[t] = E[j]; Ff[t] = F[j];
    }
    __syncthreads();
    const int p0 = c * POS;

    float runE = TE[c * DD + t];
#pragma unroll
    for (int k = POS - 1; k >= 0; --k) {
        runE = fmaf(Ee[k], h[(size_t)jj[k] * DD + t], runE);
        PSE[(size_t)(p0 + k) * DD + t] = runE;
    }
    float runF = TF[c * DD + t];
#pragma unroll
    for (int k = 0; k < POS; ++k) {
        PSF[(size_t)(p0 + k) * DD + t] = runF;
        runF = fmaf(Ff[k], h[(size_t)jj[k] * DD + t], runF);
    }
    if (t == 0) {
        float rE = sTE[c];
#pragma unroll
        for (int k = POS - 1; k >= 0; --k) { rE += Ee[k]; psE[p0 + k] = rE; }
        float rF = sTF[c];
#pragma unroll
        for (int k = 0; k < POS; ++k) { psF[p0 + k] = rF; rF += Ff[k]; }
    }
}

// ---------------------------------------------------------------- KE: output rows
__global__ __launch_bounds__(256) void ke_out(
    const float* __restrict__ h, const float* __restrict__ s1, const float* __restrict__ s2,
    const float* __restrict__ E, const float* __restrict__ F,
    const int* __restrict__ perm, const int* __restrict__ boff,
    const float* __restrict__ PSE, const float* __restrict__ PSF,
    const float* __restrict__ psE, const float* __restrict__ psF,
    const float* __restrict__ ab, float* __restrict__ out)
{
    const int i = blockIdx.x;
    const int t = threadIdx.x;
    const float c = s1[i] + ab[0];
    const float tau = -c;
    const int Bt = bucket_of(tau);
    const float A = expf(c);
    const float Alo = expf(NEG_SLOPE * c);

    const int p0 = boff[Bt], p1 = boff[Bt + 1];
    float num = A * PSE[(size_t)p1 * DD + t] + Alo * PSF[(size_t)p0 * DD + t];
    float den = A * psE[p1] + Alo * psF[p0];

    for (int p = p0; p < p1; ++p) {
        const int j = perm[p];
        const float hv = h[(size_t)j * DD + t];
        if (s2[j] >= tau) {
            const float w = A * E[j];
            num = fmaf(w, hv, num);
            den += w;
        } else {
            const float w = Alo * F[j];
            num = fmaf(w, hv, num);
            den += w;
        }
    }
    out[(size_t)i * DD + t] = num / den;
}

// ----------------------------------------------------------------
extern "C" void kernel_launch(void* const* d_in, const int* in_sizes, int n_in,
                              void* d_out, int out_size, void* d_ws, size_t ws_size,
                              hipStream_t stream)
{
    const float* x   = (const float*)d_in[0];
    const float* W   = (const float*)d_in[1];
    const float* bfc = (const float*)d_in[2];
    const float* a1  = (const float*)d_in[3];
    const float* a2  = (const float*)d_in[4];
    const float* ab  = (const float*)d_in[5];
    float* out = (float*)d_out;

    float* h   = (float*)d_ws;                      // [N][D]
    float* PSE = h + (size_t)NN * DD;               // [N+1][D]
    float* PSF = PSE + (size_t)(NN + 1) * DD;       // [N+1][D]
    float* TE  = PSF + (size_t)(NN + 1) * DD;       // [CH][D]
    float* TF  = TE + (size_t)CH * DD;              // [CH][D]
    float* s1  = TF + (size_t)CH * DD;              // [N]
    float* s2  = s1 + NN;                           // [N]
    float* E   = s2 + NN;                           // [N]
    float* F   = E + NN;                            // [N]
    float* psE = F + NN;                            // [N+1]
    float* psF = psE + (NN + 1);                    // [N+1]
    float* sTE = psF + (NN + 1);                    // [CH]
    float* sTF = sTE + CH;                          // [CH]
    int* cnt   = (int*)(sTF + CH);                  // [NB]
    int* boff  = cnt + NB;                          // [NB+1]
    int* perm  = boff + (NB + 1);                   // [N]

    hipMemsetAsync(cnt, 0, NB * sizeof(int), stream);
    ka_gemm<<<NN / 16, 256, 0, stream>>>(x, W, bfc, a1, a2, h, s1, s2, E, F, cnt);
    kb_scan<<<1, 256, 0, stream>>>(cnt, boff);
    kc_scatter<<<NN / 256, 256, 0, stream>>>(s2, cnt, perm);
    kd1_tot<<<CH, 256, 0, stream>>>(h, E, F, perm, TE, TF, sTE, sTF);
    kd2_scan<<<1, 512, 0, stream>>>(TE, TF, sTE, sTF, PSE, PSF, psE, psF);
    kd3_write<<<CH, 256, 0, stream>>>(h, E, F, perm, TE, TF, sTE, sTF, PSE, PSF, psE, psF);
    ke_out<<<NN, 256, 0, stream>>>(h, s1, s2, E, F, perm, boff, PSE, PSF, psE, psF, ab, out);
}

// Round 3
// 144.220 us; speedup vs baseline: 2.3038x; 1.2050x over previous
//
#include <hip/hip_runtime.h>
#include <math.h>

// GraphAttentionLayer, N=8192, D=256, fp32. Exact reformulation:
//   h = x@W + b ; s1 = h@a1 ; s2 = h@a2 ; c_i = s1_i + a_b
//   w_ij = [s2_j >= -c_i] exp(c_i)E_j + [s2_j < -c_i] exp(.01c_i)F_j,
//   E_j = exp(s2_j), F_j = exp(.01 s2_j).
// Counting-sort j by s2_j; position-indexed suffix/prefix scans PSE/PSF over
// sorted order; each output row = 2 vector lookups + boundary bucket. O(N*D).
// R3: ka_gemm register-blocked 4x4 (fp32 vector roofline), kd2 parallelized
// across 513 blocks (was 1 workgroup).

#define NN 8192
#define DD 256
#define NB 8192
#define CH 512           /* scan chunks */
#define POS (NN / CH)    /* 16 positions per chunk */
#define RANGE 8.0f
#define SCALE (NB / (2.0f * RANGE))
#define NEG_SLOPE 0.01f

__device__ __forceinline__ int bucket_of(float v) {
    v = fminf(fmaxf(v, -RANGE), RANGE);
    int b = (int)floorf((v + RANGE) * SCALE);
    if (b < 0) b = 0;
    if (b > NB - 1) b = NB - 1;
    return b;
}

// ---------------------------------------------------------------- KA: h = x@W+b, s1, s2, E, F, hist
// 512 blocks x 256 thr. Block tile: 16 rows x 256 cols. Thread: 4x4 register tile
// (ct=t&63 -> cols 4ct..4ct+3 ; rt=t>>6 -> rows rt*4..rt*4+3). x tile staged in LDS.
__global__ __launch_bounds__(256) void ka_gemm(
    const float* __restrict__ x, const float* __restrict__ W,
    const float* __restrict__ bfc, const float* __restrict__ a1,
    const float* __restrict__ a2,
    float* __restrict__ h, float* __restrict__ s1, float* __restrict__ s2,
    float* __restrict__ E, float* __restrict__ F, int* __restrict__ cnt)
{
    const int t = threadIdx.x;
    const int ct = t & 63;
    const int rt = t >> 6;
    const int row0 = blockIdx.x * 16;
    __shared__ float xs[16][DD];

#pragma unroll
    for (int i = 0; i < 4; ++i) {
        const int f = i * 256 + t;          // float4 index in [0,1024)
        const int r = f >> 6, c4 = f & 63;
        *reinterpret_cast<float4*>(&xs[r][c4 * 4]) =
            *reinterpret_cast<const float4*>(&x[(size_t)(row0 + r) * DD + c4 * 4]);
    }
    __syncthreads();

    float acc[4][4];
#pragma unroll
    for (int r = 0; r < 4; ++r)
#pragma unroll
        for (int c = 0; c < 4; ++c) acc[r][c] = 0.f;

#pragma unroll 2
    for (int k4 = 0; k4 < DD / 4; ++k4) {
        float4 wv[4];
#pragma unroll
        for (int kk = 0; kk < 4; ++kk)
            wv[kk] = *reinterpret_cast<const float4*>(&W[(size_t)(k4 * 4 + kk) * DD + ct * 4]);
        float4 xr[4];
#pragma unroll
        for (int r = 0; r < 4; ++r)
            xr[r] = *reinterpret_cast<const float4*>(&xs[rt * 4 + r][k4 * 4]);
#pragma unroll
        for (int kk = 0; kk < 4; ++kk) {
#pragma unroll
            for (int r = 0; r < 4; ++r) {
                const float xv = (kk == 0) ? xr[r].x : (kk == 1) ? xr[r].y : (kk == 2) ? xr[r].z : xr[r].w;
                acc[r][0] = fmaf(xv, wv[kk].x, acc[r][0]);
                acc[r][1] = fmaf(xv, wv[kk].y, acc[r][1]);
                acc[r][2] = fmaf(xv, wv[kk].z, acc[r][2]);
                acc[r][3] = fmaf(xv, wv[kk].w, acc[r][3]);
            }
        }
    }

    const float4 bv  = *reinterpret_cast<const float4*>(&bfc[ct * 4]);
    const float4 a1v = *reinterpret_cast<const float4*>(&a1[ct * 4]);
    const float4 a2v = *reinterpret_cast<const float4*>(&a2[ct * 4]);
    const int lane = t & 63;

#pragma unroll
    for (int r = 0; r < 4; ++r) {
        acc[r][0] += bv.x; acc[r][1] += bv.y; acc[r][2] += bv.z; acc[r][3] += bv.w;
        const int row = row0 + rt * 4 + r;
        float4 hv = make_float4(acc[r][0], acc[r][1], acc[r][2], acc[r][3]);
        *reinterpret_cast<float4*>(&h[(size_t)row * DD + ct * 4]) = hv;
        float v1 = acc[r][0] * a1v.x + acc[r][1] * a1v.y + acc[r][2] * a1v.z + acc[r][3] * a1v.w;
        float v2 = acc[r][0] * a2v.x + acc[r][1] * a2v.y + acc[r][2] * a2v.z + acc[r][3] * a2v.w;
#pragma unroll
        for (int off = 32; off; off >>= 1) {
            v1 += __shfl_xor(v1, off, 64);
            v2 += __shfl_xor(v2, off, 64);
        }
        if (lane == 0) {
            s1[row] = v1;
            s2[row] = v2;
            E[row] = expf(v2);
            F[row] = expf(NEG_SLOPE * v2);
            atomicAdd(&cnt[bucket_of(v2)], 1);
        }
    }
}

// ---------------------------------------------------------------- KB: exclusive scan cnt -> boff (+cursor)
__global__ __launch_bounds__(256) void kb_scan(int* __restrict__ cnt, int* __restrict__ boff)
{
    __shared__ int lds[256];
    const int t = threadIdx.x;
    const int base = t * 32;
    int loc[32];
    int s = 0;
#pragma unroll
    for (int k = 0; k < 32; ++k) { loc[k] = s; s += cnt[base + k]; }
    lds[t] = s;
    __syncthreads();
    for (int off = 1; off < 256; off <<= 1) {
        const int v = (t >= off) ? lds[t - off] : 0;
        __syncthreads();
        lds[t] += v;
        __syncthreads();
    }
    const int excl = (t > 0) ? lds[t - 1] : 0;
#pragma unroll
    for (int k = 0; k < 32; ++k) {
        const int val = excl + loc[k];
        boff[base + k] = val;
        cnt[base + k] = val; // scatter cursor
    }
    if (t == 0) boff[NB] = NN;
}

// ---------------------------------------------------------------- KC: counting-sort scatter
__global__ __launch_bounds__(256) void kc_scatter(
    const float* __restrict__ s2, int* __restrict__ cursor, int* __restrict__ perm)
{
    const int j = blockIdx.x * blockDim.x + threadIdx.x;
    if (j < NN) {
        const int b = bucket_of(s2[j]);
        const int p = atomicAdd(&cursor[b], 1);
        perm[p] = j;
    }
}

// ---------------------------------------------------------------- KD1: per-chunk totals over sorted positions
__global__ __launch_bounds__(256) void kd1_tot(
    const float* __restrict__ h, const float* __restrict__ E, const float* __restrict__ F,
    const int* __restrict__ perm,
    float* __restrict__ TE, float* __restrict__ TF,
    float* __restrict__ sTE, float* __restrict__ sTF)
{
    const int c = blockIdx.x;
    const int t = threadIdx.x;
    __shared__ int jj[POS];
    __shared__ float Ee[POS], Ff[POS];
    if (t < POS) {
        const int j = perm[c * POS + t];
        jj[t] = j; Ee[t] = E[j]; Ff[t] = F[j];
    }
    __syncthreads();
    float te = 0.f, tf = 0.f;
#pragma unroll
    for (int k = 0; k < POS; ++k) {
        const float hv = h[(size_t)jj[k] * DD + t];
        te = fmaf(Ee[k], hv, te);
        tf = fmaf(Ff[k], hv, tf);
    }
    TE[c * DD + t] = te;
    TF[c * DD + t] = tf;
    if (t == 0) {
        float se = 0.f, sf = 0.f;
#pragma unroll
        for (int k = 0; k < POS; ++k) { se += Ee[k]; sf += Ff[k]; }
        sTE[c] = se; sTF[c] = sf;
    }
}

// ---------------------------------------------------------------- KD2: chunk scans -> exclusive bases
// 513 blocks x 512 thr. b<256: suffix-scan TE column d=b. 256<=b<512: prefix-scan
// TF column d=b-256. b==512: scalar sTE/sTF scans + psE/psF tails.
__global__ __launch_bounds__(512) void kd2_scan(
    float* __restrict__ TE, float* __restrict__ TF,
    float* __restrict__ sTE, float* __restrict__ sTF,
    float* __restrict__ PSE, float* __restrict__ PSF,
    float* __restrict__ psE, float* __restrict__ psF)
{
    const int t = threadIdx.x;
    const int b = blockIdx.x;
    __shared__ float lds[CH];

    if (b < 512) {
        const bool isE = (b < 256);
        const int d = isE ? b : (b - 256);
        float* __restrict__ A = isE ? TE : TF;
        const float v = A[(size_t)t * DD + d];
        const int pos = isE ? (CH - 1 - t) : t;   // reverse order for suffix scan
        lds[pos] = v;
        __syncthreads();
        for (int off = 1; off < CH; off <<= 1) {
            const float add = (pos >= off) ? lds[pos - off] : 0.f;
            __syncthreads();
            lds[pos] += add;
            __syncthreads();
        }
        const float incl = lds[pos];
        A[(size_t)t * DD + d] = incl - v;          // exclusive base for chunk t
        if (t == 0) {
            if (isE) PSE[(size_t)NN * DD + d] = 0.f;
            else     PSF[(size_t)NN * DD + d] = lds[CH - 1]; // full prefix total
        }
    } else {
        const float vE = sTE[t];
        const float vF = sTF[t];
        // suffix scan of sTE
        lds[CH - 1 - t] = vE;
        __syncthreads();
        for (int off = 1; off < CH; off <<= 1) {
            const int pos = CH - 1 - t;
            const float add = (pos >= off) ? lds[pos - off] : 0.f;
            __syncthreads();
            lds[pos] += add;
            __syncthreads();
        }
        const float inclE = lds[CH - 1 - t];
        __syncthreads();
        // prefix scan of sTF
        lds[t] = vF;
        __syncthreads();
        for (int off = 1; off < CH; off <<= 1) {
            const float add = (t >= off) ? lds[t - off] : 0.f;
            __syncthreads();
            lds[t] += add;
            __syncthreads();
        }
        const float inclF = lds[t];
        const float totF = lds[CH - 1];
        sTE[t] = inclE - vE;
        sTF[t] = inclF - vF;
        if (t == 0) { psE[NN] = 0.f; psF[NN] = totF; }
    }
}

// ---------------------------------------------------------------- KD3: position-indexed PSE/PSF (+ scalar psE/psF)
__global__ __launch_bounds__(256) void kd3_write(
    const float* __restrict__ h, const float* __restrict__ E, const float* __restrict__ F,
    const int* __restrict__ perm,
    const float* __restrict__ TE, const float* __restrict__ TF,
    const float* __restrict__ sTE, const float* __restrict__ sTF,
    float* __restrict__ PSE, float* __restrict__ PSF,
    float* __restrict__ psE, float* __restrict__ psF)
{
    const int c = blockIdx.x;
    const int t = threadIdx.x;
    __shared__ int jj[POS];
    __shared__ float Ee[POS], Ff[POS];
    if (t < POS) {
        const int j = perm[c * POS + t];
        jj[t] = j; Ee[t] = E[j]; Ff[t] = F[j];
    }
    __syncthreads();
    const int p0 = c * POS;

    float runE = TE[c * DD + t];
#pragma unroll
    for (int k = POS - 1; k >= 0; --k) {
        runE = fmaf(Ee[k], h[(size_t)jj[k] * DD + t], runE);
        PSE[(size_t)(p0 + k) * DD + t] = runE;
    }
    float runF = TF[c * DD + t];
#pragma unroll
    for (int k = 0; k < POS; ++k) {
        PSF[(size_t)(p0 + k) * DD + t] = runF;
        runF = fmaf(Ff[k], h[(size_t)jj[k] * DD + t], runF);
    }
    if (t == 0) {
        float rE = sTE[c];
#pragma unroll
        for (int k = POS - 1; k >= 0; --k) { rE += Ee[k]; psE[p0 + k] = rE; }
        float rF = sTF[c];
#pragma unroll
        for (int k = 0; k < POS; ++k) { psF[p0 + k] = rF; rF += Ff[k]; }
    }
}

// ---------------------------------------------------------------- KE: output rows
__global__ __launch_bounds__(256) void ke_out(
    const float* __restrict__ h, const float* __restrict__ s1, const float* __restrict__ s2,
    const float* __restrict__ E, const float* __restrict__ F,
    const int* __restrict__ perm, const int* __restrict__ boff,
    const float* __restrict__ PSE, const float* __restrict__ PSF,
    const float* __restrict__ psE, const float* __restrict__ psF,
    const float* __restrict__ ab, float* __restrict__ out)
{
    const int i = blockIdx.x;
    const int t = threadIdx.x;
    const float c = s1[i] + ab[0];
    const float tau = -c;
    const int Bt = bucket_of(tau);
    const float A = expf(c);
    const float Alo = expf(NEG_SLOPE * c);

    const int p0 = boff[Bt], p1 = boff[Bt + 1];
    float num = A * PSE[(size_t)p1 * DD + t] + Alo * PSF[(size_t)p0 * DD + t];
    float den = A * psE[p1] + Alo * psF[p0];

    for (int p = p0; p < p1; ++p) {
        const int j = perm[p];
        const float hv = h[(size_t)j * DD + t];
        if (s2[j] >= tau) {
            const float w = A * E[j];
            num = fmaf(w, hv, num);
            den += w;
        } else {
            const float w = Alo * F[j];
            num = fmaf(w, hv, num);
            den += w;
        }
    }
    out[(size_t)i * DD + t] = num / den;
}

// ----------------------------------------------------------------
extern "C" void kernel_launch(void* const* d_in, const int* in_sizes, int n_in,
                              void* d_out, int out_size, void* d_ws, size_t ws_size,
                              hipStream_t stream)
{
    const float* x   = (const float*)d_in[0];
    const float* W   = (const float*)d_in[1];
    const float* bfc = (const float*)d_in[2];
    const float* a1  = (const float*)d_in[3];
    const float* a2  = (const float*)d_in[4];
    const float* ab  = (const float*)d_in[5];
    float* out = (float*)d_out;

    float* h   = (float*)d_ws;                      // [N][D]
    float* PSE = h + (size_t)NN * DD;               // [N+1][D]
    float* PSF = PSE + (size_t)(NN + 1) * DD;       // [N+1][D]
    float* TE  = PSF + (size_t)(NN + 1) * DD;       // [CH][D]
    float* TF  = TE + (size_t)CH * DD;              // [CH][D]
    float* s1  = TF + (size_t)CH * DD;              // [N]
    float* s2  = s1 + NN;                           // [N]
    float* E   = s2 + NN;                           // [N]
    float* F   = E + NN;                            // [N]
    float* psE = F + NN;                            // [N+1]
    float* psF = psE + (NN + 1);                    // [N+1]
    float* sTE = psF + (NN + 1);                    // [CH]
    float* sTF = sTE + CH;                          // [CH]
    int* cnt   = (int*)(sTF + CH);                  // [NB]
    int* boff  = cnt + NB;                          // [NB+1]
    int* perm  = boff + (NB + 1);                   // [N]

    hipMemsetAsync(cnt, 0, NB * sizeof(int), stream);
    ka_gemm<<<NN / 16, 256, 0, stream>>>(x, W, bfc, a1, a2, h, s1, s2, E, F, cnt);
    kb_scan<<<1, 256, 0, stream>>>(cnt, boff);
    kc_scatter<<<NN / 256, 256, 0, stream>>>(s2, cnt, perm);
    kd1_tot<<<CH, 256, 0, stream>>>(h, E, F, perm, TE, TF, sTE, sTF);
    kd2_scan<<<513, 512, 0, stream>>>(TE, TF, sTE, sTF, PSE, PSF, psE, psF);
    kd3_write<<<CH, 256, 0, stream>>>(h, E, F, perm, TE, TF, sTE, sTF, PSE, PSF, psE, psF);
    ke_out<<<NN, 256, 0, stream>>>(h, s1, s2, E, F, perm, boff, PSE, PSF, psE, psF, ab, out);
}